// Round 1
// baseline (183.752 us; speedup 1.0000x reference)
//
#include <hip/hip_runtime.h>

// RandomAttention: B=2, S=2048, NH=8, H=64, NKEYS=64, fp32.
// One wave per (b, q, head). Phase 1: lane = key n (scattered K gather,
// q broadcast from LDS). Softmax across wave. Phase 2: lane = h
// (coalesced V rows, p/idx broadcast via readlane-shuffles).

#define BB 2
#define SS 2048
#define NHH 8
#define HH 64
#define NKEYS 64

__global__ __launch_bounds__(256, 8) void rand_attn_kernel(
    const float* __restrict__ q, const float* __restrict__ k,
    const float* __restrict__ v, const int* __restrict__ idx,
    float* __restrict__ out) {
  const int warp = threadIdx.x >> 6;
  const int lane = threadIdx.x & 63;
  const int w = blockIdx.x * 4 + warp;   // global wave id in [0, B*S*NH)
  const int e = w & (NHH - 1);           // head
  const int bq = w >> 3;                 // b*S + s
  const int b = bq >> 11;                // S = 2048

  __shared__ float qs[4][HH];

  // Stage this wave's q row into LDS (64 floats, coalesced).
  const float* qrow = q + ((size_t)bq * NHH + e) * HH;
  qs[warp][lane] = qrow[lane];

  // Each lane owns one random key index.
  const int myidx = idx[(size_t)bq * NKEYS + lane];
  const float* kb = k + (size_t)b * (SS * NHH * HH);
  const float* vb = v + (size_t)b * (SS * NHH * HH);
  const float4* krow4 =
      (const float4*)(kb + ((size_t)myidx * NHH + e) * HH);

  __syncthreads();

  // Phase 1: score[lane] = scale * dot(q[e,:], k[idx[lane], e, :])
  const float4* q4 = (const float4*)qs[warp];
  float sc = 0.f;
#pragma unroll
  for (int i = 0; i < HH / 4; ++i) {
    float4 kv = krow4[i];   // 16B per lane, 64 scattered rows (L2-served)
    float4 qv = q4[i];      // same-address LDS broadcast, conflict-free
    sc += kv.x * qv.x;
    sc += kv.y * qv.y;
    sc += kv.z * qv.z;
    sc += kv.w * qv.w;
  }
  sc *= 0.125f;  // H^-0.5, H = 64

  // Softmax over the 64 lanes (keys).
  float m = sc;
#pragma unroll
  for (int off = 32; off; off >>= 1) m = fmaxf(m, __shfl_xor(m, off, 64));
  float p = __expf(sc - m);
  float s = p;
#pragma unroll
  for (int off = 32; off; off >>= 1) s += __shfl_xor(s, off, 64);
  p /= s;

  // Phase 2: lane = h. out[h] = sum_n p[n] * v[idx[n], e, h].
  float acc0 = 0.f, acc1 = 0.f, acc2 = 0.f, acc3 = 0.f;
#pragma unroll
  for (int n = 0; n < NKEYS; n += 4) {
    float p0 = __shfl(p, n + 0, 64);     // uniform src lane -> v_readlane
    float p1 = __shfl(p, n + 1, 64);
    float p2 = __shfl(p, n + 2, 64);
    float p3 = __shfl(p, n + 3, 64);
    int i0 = __shfl(myidx, n + 0, 64);
    int i1 = __shfl(myidx, n + 1, 64);
    int i2 = __shfl(myidx, n + 2, 64);
    int i3 = __shfl(myidx, n + 3, 64);
    acc0 += p0 * vb[((size_t)i0 * NHH + e) * HH + lane];  // coalesced 256B
    acc1 += p1 * vb[((size_t)i1 * NHH + e) * HH + lane];
    acc2 += p2 * vb[((size_t)i2 * NHH + e) * HH + lane];
    acc3 += p3 * vb[((size_t)i3 * NHH + e) * HH + lane];
  }

  out[((size_t)bq * NHH + e) * HH + lane] = (acc0 + acc1) + (acc2 + acc3);
}

extern "C" void kernel_launch(void* const* d_in, const int* in_sizes, int n_in,
                              void* d_out, int out_size, void* d_ws,
                              size_t ws_size, hipStream_t stream) {
  const float* q = (const float*)d_in[0];
  const float* k = (const float*)d_in[1];
  const float* v = (const float*)d_in[2];
  const int* idx = (const int*)d_in[3];
  float* out = (float*)d_out;

  // B*S*NH = 32768 waves; 4 waves per 256-thread block -> 8192 blocks.
  const int n_blocks = (BB * SS * NHH) / 4;
  rand_attn_kernel<<<n_blocks, 256, 0, stream>>>(q, k, v, idx, out);
}

// Round 2
// 115.296 us; speedup vs baseline: 1.5937x; 1.5937x over previous
//
#include <hip/hip_runtime.h>

// RandomAttention: B=2, S=2048, NH=8, H=64, NKEYS=64, fp32.
// One wave per (b, q, head). Lane remap: g = lane>>4 (key group),
// c = lane&15 (float4 chunk of the 64-float row). Each 16-lane group
// owns one key row per iteration -> every K/V wave-load covers 4 full
// 256B rows (8 cache lines, 100% utilized) instead of 64 scattered
// 16B touches. Scores finish with 4 intra-group DPP shuffles; V is
// accumulated as per-group float4 partials, one cross-group reduce at
// the end. Indices broadcast with ds_bpermute (no global re-reads).

#define BB 2
#define SS 2048
#define NHH 8
#define HH 64
#define NKEYS 64

__global__ __launch_bounds__(256, 4) void rand_attn_kernel(
    const float* __restrict__ q, const float* __restrict__ k,
    const float* __restrict__ v, const int* __restrict__ idx,
    float* __restrict__ out) {
  const int warp = threadIdx.x >> 6;
  const int lane = threadIdx.x & 63;
  const int g = lane >> 4;   // key group 0..3 (key n == 4*j + g)
  const int c = lane & 15;   // float4 chunk within the 64-float row
  const int w = blockIdx.x * 4 + warp;   // global wave id in [0, B*S*NH)
  const int e = w & (NHH - 1);           // head
  const int bq = w >> 3;                 // b*S + s
  const int b = bq >> 11;                // S = 2048

  // q chunk for this lane (replicated across the 4 groups), pre-scaled.
  const float* qrow = q + ((size_t)bq * NHH + e) * HH;
  float4 q4 = ((const float4*)qrow)[c];
  q4.x *= 0.125f; q4.y *= 0.125f; q4.z *= 0.125f; q4.w *= 0.125f;

  // Lane n holds idx[bq, n] (coalesced 256B load).
  const int myidx = idx[(size_t)bq * NKEYS + lane];
  const float* kb = k + (size_t)b * (SS * NHH * HH);
  const float* vb = v + (size_t)b * (SS * NHH * HH);

  int vi[16];     // this group's key indices, one per iteration
  float sc[16];   // this group's scores (all 16 lanes of a group agree)

  // Phase 1: scores. Iteration j: group g computes S[4j+g].
#pragma unroll
  for (int j = 0; j < 16; ++j) {
    const int n = 4 * j + g;
    vi[j] = __builtin_amdgcn_ds_bpermute(n << 2, myidx);
    const float4* kr = (const float4*)(kb + ((size_t)vi[j] * NHH + e) * HH);
    float4 kv = kr[c];   // 4 full rows / wave-load, fully-utilized lines
    float t = kv.x * q4.x + kv.y * q4.y + kv.z * q4.z + kv.w * q4.w;
    t += __shfl_xor(t, 1, 64);   // intra-group (16-lane) reduce: DPP
    t += __shfl_xor(t, 2, 64);
    t += __shfl_xor(t, 4, 64);
    t += __shfl_xor(t, 8, 64);
    sc[j] = t;
  }

  // Softmax over all 64 keys (16 per lane within group + cross-group).
  float m = sc[0];
#pragma unroll
  for (int j = 1; j < 16; ++j) m = fmaxf(m, sc[j]);
  m = fmaxf(m, __shfl_xor(m, 16, 64));
  m = fmaxf(m, __shfl_xor(m, 32, 64));
  float ssum = 0.f;
#pragma unroll
  for (int j = 0; j < 16; ++j) {
    sc[j] = __expf(sc[j] - m);
    ssum += sc[j];
  }
  ssum += __shfl_xor(ssum, 16, 64);
  ssum += __shfl_xor(ssum, 32, 64);
  const float inv = 1.0f / ssum;
#pragma unroll
  for (int j = 0; j < 16; ++j) sc[j] *= inv;

  // Phase 2: PV. Group g accumulates its keys' float4 partial.
  float4 acc = make_float4(0.f, 0.f, 0.f, 0.f);
#pragma unroll
  for (int j = 0; j < 16; ++j) {
    const float4* vr = (const float4*)(vb + ((size_t)vi[j] * NHH + e) * HH);
    float4 vv = vr[c];
    acc.x += sc[j] * vv.x;
    acc.y += sc[j] * vv.y;
    acc.z += sc[j] * vv.z;
    acc.w += sc[j] * vv.w;
  }
  // Cross-group sum (xor 16, 32) -> every lane has the full result.
  acc.x += __shfl_xor(acc.x, 16, 64);
  acc.y += __shfl_xor(acc.y, 16, 64);
  acc.z += __shfl_xor(acc.z, 16, 64);
  acc.w += __shfl_xor(acc.w, 16, 64);
  acc.x += __shfl_xor(acc.x, 32, 64);
  acc.y += __shfl_xor(acc.y, 32, 64);
  acc.z += __shfl_xor(acc.z, 32, 64);
  acc.w += __shfl_xor(acc.w, 32, 64);

  if (g == 0) {
    ((float4*)(out + ((size_t)bq * NHH + e) * HH))[c] = acc;
  }
}

extern "C" void kernel_launch(void* const* d_in, const int* in_sizes, int n_in,
                              void* d_out, int out_size, void* d_ws,
                              size_t ws_size, hipStream_t stream) {
  const float* q = (const float*)d_in[0];
  const float* k = (const float*)d_in[1];
  const float* v = (const float*)d_in[2];
  const int* idx = (const int*)d_in[3];
  float* out = (float*)d_out;

  // B*S*NH = 32768 waves; 4 waves per 256-thread block -> 8192 blocks.
  const int n_blocks = (BB * SS * NHH) / 4;
  rand_attn_kernel<<<n_blocks, 256, 0, stream>>>(q, k, v, idx, out);
}